// Round 9
// baseline (212.143 us; speedup 1.0000x reference)
//
#include <hip/hip_runtime.h>
#include <hip/hip_bf16.h>

#define NB 8
#define SEQ 512
#define DMODEL 1024
#define NHEAD 16
#define HDIM 64
typedef __hip_bfloat16 bf16;
typedef __attribute__((ext_vector_type(8))) short short8;
typedef __attribute__((ext_vector_type(4))) float f32x4;

__device__ __forceinline__ void glds16(const void* g, void* l) {
    __builtin_amdgcn_global_load_lds(
        (const __attribute__((address_space(1))) unsigned int*)g,
        (__attribute__((address_space(3))) unsigned int*)l, 16, 0, 0);
}

// ---------------- fp32 -> bf16 cast (X), 8 elems/thread
__global__ __launch_bounds__(256)
void cast_bf16_k(const float* __restrict__ X, bf16* __restrict__ Xb) {
    int i = (blockIdx.x * 256 + threadIdx.x) * 8;
    float4 v0 = *(const float4*)&X[i];
    float4 v1 = *(const float4*)&X[i + 4];
    bf16 o[8];
    o[0] = __float2bfloat16(v0.x); o[1] = __float2bfloat16(v0.y);
    o[2] = __float2bfloat16(v0.z); o[3] = __float2bfloat16(v0.w);
    o[4] = __float2bfloat16(v1.x); o[5] = __float2bfloat16(v1.y);
    o[6] = __float2bfloat16(v1.z); o[7] = __float2bfloat16(v1.w);
    *(uint4*)&Xb[i] = *(uint4*)o;
}

// ---------------- fp32 [R][C] -> bf16 [C][R] transpose (W -> W^T)
__global__ __launch_bounds__(256)
void transpose_cast_k(const float* __restrict__ W, bf16* __restrict__ Wt,
                      int R, int C) {
    __shared__ float t[64][65];
    int k0 = blockIdx.y * 64, n0 = blockIdx.x * 64;
    int c = threadIdx.x & 63, r = threadIdx.x >> 6;
    #pragma unroll 4
    for (int i = 0; i < 16; ++i)
        t[r + i * 4][c] = W[(size_t)(k0 + r + i * 4) * C + n0 + c];
    __syncthreads();
    #pragma unroll 4
    for (int i = 0; i < 16; ++i)
        Wt[(size_t)(n0 + r + i * 4) * R + k0 + c] = __float2bfloat16(t[c][r + i * 4]);
}

// ================= MFMA GEMM mainloop, double-buffered 2-phase ============
// C[128x128]/block, 4 waves (2x2), BK=64, 16 K-steps (K=1024).
// T3-minimum recipe: STAGE(next) issued BEFORE compute(cur); ONE
// vmcnt(0)+barrier per K-step. LDS 2x(16+16)KB. Swizzle per rule #21.
#define GEMM_MAINLOOP_DB(Agp, Bgp)                                            \
    __shared__ __align__(16) short Asm[2][128 * 64];                          \
    __shared__ __align__(16) short Bsm[2][128 * 64];                          \
    int tid = threadIdx.x;                                                    \
    int lane = tid & 63, wid = tid >> 6;                                      \
    int wr = wid >> 1, wc = wid & 1;                                          \
    int lj = lane & 15, li = lane >> 4;                                       \
    int srow = lane >> 3, ssl = lane & 7;                                     \
    f32x4 acc[4][4] = {};                                                     \
    _Pragma("unroll")                                                         \
    for (int q = 0; q < 4; ++q) {                                             \
        int seg = wid * 4 + q;                                                \
        int row = seg * 8 + srow;                                             \
        int cg = ssl ^ (row & 7);                                             \
        glds16(Agp + ((size_t)(m0 + row) * 1024 + cg * 8),                    \
               (char*)Asm[0] + seg * 1024);                                   \
        glds16(Bgp + ((size_t)(n0 + row) * 1024 + cg * 8),                    \
               (char*)Bsm[0] + seg * 1024);                                   \
    }                                                                         \
    __syncthreads();                                                          \
    for (int ks = 0; ks < 16; ++ks) {                                         \
        int cur = ks & 1;                                                     \
        if (ks + 1 < 16) {                                                    \
            int k0 = (ks + 1) * 64;                                           \
            _Pragma("unroll")                                                 \
            for (int q = 0; q < 4; ++q) {                                     \
                int seg = wid * 4 + q;                                        \
                int row = seg * 8 + srow;                                     \
                int cg = ssl ^ (row & 7);                                     \
                glds16(Agp + ((size_t)(m0 + row) * 1024 + k0 + cg * 8),       \
                       (char*)Asm[cur ^ 1] + seg * 1024);                     \
                glds16(Bgp + ((size_t)(n0 + row) * 1024 + k0 + cg * 8),       \
                       (char*)Bsm[cur ^ 1] + seg * 1024);                     \
            }                                                                 \
        }                                                                     \
        _Pragma("unroll")                                                     \
        for (int kk = 0; kk < 2; ++kk) {                                      \
            short8 af[4], bfr[4];                                             \
            _Pragma("unroll")                                                 \
            for (int mf = 0; mf < 4; ++mf) {                                  \
                int r = wr * 64 + mf * 16 + lj;                               \
                int ck = kk * 4 + li;                                         \
                af[mf] = *(const short8*)((const char*)Asm[cur] +             \
                          (r * 128 + ((ck ^ (r & 7)) * 16)));                 \
            }                                                                 \
            _Pragma("unroll")                                                 \
            for (int nf = 0; nf < 4; ++nf) {                                  \
                int r = wc * 64 + nf * 16 + lj;                               \
                int ck = kk * 4 + li;                                         \
                bfr[nf] = *(const short8*)((const char*)Bsm[cur] +            \
                          (r * 128 + ((ck ^ (r & 7)) * 16)));                 \
            }                                                                 \
            _Pragma("unroll")                                                 \
            for (int mf = 0; mf < 4; ++mf)                                    \
                _Pragma("unroll")                                             \
                for (int nf = 0; nf < 4; ++nf)                                \
                    acc[mf][nf] = __builtin_amdgcn_mfma_f32_16x16x32_bf16(    \
                        af[mf], bfr[nf], acc[mf][nf], 0, 0, 0);               \
        }                                                                     \
        __syncthreads();                                                      \
    }

// ---------------- QKV GEMM (M=4096, N=3072) + bias + RoPE epilogue
// V is written TRANSPOSED: Vt[b,h,d,s] so attention can stage it as B-operand.
__global__ __launch_bounds__(256)
void qkv_mfma_k(const bf16* __restrict__ Xb, const bf16* __restrict__ Wt,
                const float* __restrict__ bias,
                bf16* __restrict__ Qb, bf16* __restrict__ Kb, bf16* __restrict__ Vt) {
    int m0 = blockIdx.y * 128, n0 = blockIdx.x * 128;
    GEMM_MAINLOOP_DB(Xb, Wt)
    int ncol = n0 + wc * 64;
    int c = ncol >> 10;
    int h = (ncol & 1023) >> 6;
    #pragma unroll
    for (int nf = 0; nf < 2; ++nf) {
        int p = nf * 16 + lj;
        float b1 = bias[ncol + p], b2 = bias[ncol + p + 32];
        float freq = __expf(-(float)p * 0.28782313662425574f); // 10000^(-p/32)
        #pragma unroll
        for (int mf = 0; mf < 4; ++mf) {
            #pragma unroll
            for (int j = 0; j < 4; ++j) {
                int m = m0 + wr * 64 + mf * 16 + li * 4 + j;
                int bb = m >> 9, s = m & 511;
                float v1 = acc[mf][nf][j] + b1;
                float v2 = acc[mf][nf + 2][j] + b2;
                if (c == 2) {
                    size_t tb = (size_t)(bb * NHEAD + h) * HDIM;
                    Vt[(tb + p) * SEQ + s]      = __float2bfloat16(v1);
                    Vt[(tb + p + 32) * SEQ + s] = __float2bfloat16(v2);
                } else {
                    float sv, cv;
                    sincosf((float)s * freq, &sv, &cv);
                    float o1 = v1 * cv - v2 * sv;
                    float o2 = v1 * sv + v2 * cv;
                    bf16* dst = (c == 0) ? Qb : Kb;
                    size_t base = ((size_t)(bb * NHEAD + h) * SEQ + s) * HDIM;
                    dst[base + p]      = __float2bfloat16(o1);
                    dst[base + p + 32] = __float2bfloat16(o2);
                }
            }
        }
    }
}

// ---------------- out GEMM (M=4096, N=1024) + bias -> fp32
__global__ __launch_bounds__(256)
void out_mfma_k(const bf16* __restrict__ Ab, const bf16* __restrict__ Wt,
                const float* __restrict__ bias, float* __restrict__ out) {
    int m0 = blockIdx.y * 128, n0 = blockIdx.x * 128;
    GEMM_MAINLOOP_DB(Ab, Wt)
    int col0 = n0 + wc * 64;
    #pragma unroll
    for (int nf = 0; nf < 4; ++nf) {
        int col = col0 + nf * 16 + lj;
        float bv = bias[col];
        #pragma unroll
        for (int mf = 0; mf < 4; ++mf)
            #pragma unroll
            for (int j = 0; j < 4; ++j) {
                int m = m0 + wr * 64 + mf * 16 + li * 4 + j;
                out[(size_t)m * DMODEL + col] = acc[mf][nf][j] + bv;
            }
    }
}

// ---------------- MFMA flash attention, double-buffered K/V ---------------
// grid = (B*H)*8; block = 64 q-rows of one (b,h); 4 waves, wave w owns rows
// w*16..w*16+16. K-tiles of 64 double-buffered; ONE barrier per tile.
__global__ __launch_bounds__(256)
void attn_mfma_k(const bf16* __restrict__ Qb, const bf16* __restrict__ Kb,
                 const bf16* __restrict__ Vt, bf16* __restrict__ Ab) {
    __shared__ __align__(16) short Qsm[64 * 64];
    __shared__ __align__(16) short Ksm[2][64 * 64];
    __shared__ __align__(16) short Vsm[2][64 * 64];
    __shared__ __align__(16) short Psm[64 * 64];
    int tid = threadIdx.x;
    int lane = tid & 63, wid = tid >> 6;
    int lj = lane & 15, li = lane >> 4;
    int bh = blockIdx.x >> 3, qt = blockIdx.x & 7;
    const bf16* Qp = Qb + ((size_t)bh * SEQ + qt * 64) * HDIM;
    const bf16* Kp = Kb + (size_t)bh * SEQ * HDIM;
    const bf16* Vp = Vt + (size_t)bh * HDIM * SEQ;
    int srow = lane >> 3, ssl = lane & 7;
    #pragma unroll
    for (int q = 0; q < 2; ++q) {                 // stage Q + tile 0 K/V
        int seg = wid * 2 + q;
        int row = seg * 8 + srow;
        int cg = ssl ^ (row & 7);
        glds16(Qp + ((size_t)row * 64 + cg * 8), (char*)Qsm + seg * 1024);
        glds16(Kp + ((size_t)row * 64 + cg * 8), (char*)Ksm[0] + seg * 1024);
        glds16(Vp + ((size_t)row * SEQ + cg * 8), (char*)Vsm[0] + seg * 1024);
    }
    float m_[4], l_[4];
    f32x4 acc_o[4] = {};
    #pragma unroll
    for (int j = 0; j < 4; ++j) { m_[j] = -1e30f; l_[j] = 0.f; }
    __syncthreads();
    for (int kt = 0; kt < 8; ++kt) {
        int cur = kt & 1;
        if (kt + 1 < 8) {                         // stage next K/V tile
            #pragma unroll
            for (int q = 0; q < 2; ++q) {
                int seg = wid * 2 + q;
                int row = seg * 8 + srow;
                int cg = ssl ^ (row & 7);
                glds16(Kp + ((size_t)((kt + 1) * 64 + row) * 64 + cg * 8),
                       (char*)Ksm[cur ^ 1] + seg * 1024);
                glds16(Vp + ((size_t)row * SEQ + (kt + 1) * 64 + cg * 8),
                       (char*)Vsm[cur ^ 1] + seg * 1024);
            }
        }
        // S = Q K^T
        f32x4 sacc[4] = {};
        #pragma unroll
        for (int kk = 0; kk < 2; ++kk) {
            int r = wid * 16 + lj;
            int ck = kk * 4 + li;
            short8 af = *(const short8*)((const char*)Qsm +
                         (r * 128 + ((ck ^ (r & 7)) * 16)));
            #pragma unroll
            for (int nf = 0; nf < 4; ++nf) {
                int rb = nf * 16 + lj;
                short8 kf = *(const short8*)((const char*)Ksm[cur] +
                             (rb * 128 + ((ck ^ (rb & 7)) * 16)));
                sacc[nf] = __builtin_amdgcn_mfma_f32_16x16x32_bf16(af, kf, sacc[nf], 0, 0, 0);
            }
        }
        // online softmax: row = wid*16 + li*4 + j
        float p[4][4];
        #pragma unroll
        for (int j = 0; j < 4; ++j) {
            float s0 = sacc[0][j] * 0.125f, s1 = sacc[1][j] * 0.125f;
            float s2 = sacc[2][j] * 0.125f, s3 = sacc[3][j] * 0.125f;
            float tm = fmaxf(fmaxf(s0, s1), fmaxf(s2, s3));
            tm = fmaxf(tm, __shfl_xor(tm, 1));
            tm = fmaxf(tm, __shfl_xor(tm, 2));
            tm = fmaxf(tm, __shfl_xor(tm, 4));
            tm = fmaxf(tm, __shfl_xor(tm, 8));
            float mn = fmaxf(m_[j], tm);
            float sc = __expf(m_[j] - mn);
            p[0][j] = __expf(s0 - mn); p[1][j] = __expf(s1 - mn);
            p[2][j] = __expf(s2 - mn); p[3][j] = __expf(s3 - mn);
            float ts = p[0][j] + p[1][j] + p[2][j] + p[3][j];
            ts += __shfl_xor(ts, 1); ts += __shfl_xor(ts, 2);
            ts += __shfl_xor(ts, 4); ts += __shfl_xor(ts, 8);
            l_[j] = l_[j] * sc + ts;
            m_[j] = mn;
            acc_o[0][j] *= sc; acc_o[1][j] *= sc;
            acc_o[2][j] *= sc; acc_o[3][j] *= sc;
        }
        // P -> LDS (bf16, swizzled; wave-local rows — no cross-wave hazard)
        #pragma unroll
        for (int nf = 0; nf < 4; ++nf)
            #pragma unroll
            for (int j = 0; j < 4; ++j) {
                int row = wid * 16 + li * 4 + j;
                int col = nf * 16 + lj;
                int cl = col >> 3;
                *(bf16*)((char*)Psm + row * 128 + ((cl ^ (row & 7)) * 16) +
                         (col & 7) * 2) = __float2bfloat16(p[nf][j]);
            }
        // O += P V
        #pragma unroll
        for (int kk = 0; kk < 2; ++kk) {
            int r = wid * 16 + lj;
            int ck = kk * 4 + li;
            short8 pa = *(const short8*)((const char*)Psm +
                         (r * 128 + ((ck ^ (r & 7)) * 16)));
            #pragma unroll
            for (int nf = 0; nf < 4; ++nf) {
                int rb = nf * 16 + lj;
                short8 vf = *(const short8*)((const char*)Vsm[cur] +
                             (rb * 128 + ((ck ^ (rb & 7)) * 16)));
                acc_o[nf] = __builtin_amdgcn_mfma_f32_16x16x32_bf16(pa, vf, acc_o[nf], 0, 0, 0);
            }
        }
        __syncthreads();   // drains K/V[cur] reads + next-tile glds writes
    }
    // epilogue: normalize, write bf16 to (B,S,D) for out_mfma
    int b = bh >> 4, h = bh & 15;
    #pragma unroll
    for (int j = 0; j < 4; ++j) {
        float inv = 1.0f / l_[j];
        int s = qt * 64 + wid * 16 + li * 4 + j;
        #pragma unroll
        for (int nf = 0; nf < 4; ++nf) {
            int d = nf * 16 + lj;
            Ab[((size_t)b * SEQ + s) * DMODEL + h * 64 + d] =
                __float2bfloat16(acc_o[nf][j] * inv);
        }
    }
}

extern "C" void kernel_launch(void* const* d_in, const int* in_sizes, int n_in,
                              void* d_out, int out_size, void* d_ws, size_t ws_size,
                              hipStream_t stream) {
    const float *x = nullptr, *Wqkv = nullptr, *bqkv = nullptr,
                *Wout = nullptr, *bout = nullptr;
    for (int i = 0; i < n_in; ++i) {
        switch (in_sizes[i]) {
            case NB * SEQ * DMODEL:   x    = (const float*)d_in[i]; break;
            case DMODEL * 3 * DMODEL: Wqkv = (const float*)d_in[i]; break;
            case 3 * DMODEL:          bqkv = (const float*)d_in[i]; break;
            case DMODEL * DMODEL:     Wout = (const float*)d_in[i]; break;
            case DMODEL:              bout = (const float*)d_in[i]; break;
        }
    }
    if (!x)    x    = (const float*)d_in[0];
    if (!Wqkv) Wqkv = (const float*)d_in[1];
    if (!bqkv) bqkv = (const float*)d_in[2];
    if (!Wout) Wout = (const float*)d_in[3];
    if (!bout) bout = (const float*)d_in[4];
    float* out = (float*)d_out;

    // ws layout, 40 MB peak (proven footprint):
    // [0,8M)   Xb bf16 — dead after qkv_mfma; Ab (bf16) aliases it
    // [8,14M)  Wqkv_t | [14,16M) Wout_t | [16,24M) Qb | [24,32M) Kb | [32,40M) Vt
    char* ws = (char*)d_ws;
    bf16* Xb     = (bf16*)(ws);
    bf16* Ab     = (bf16*)(ws);                    // aliases Xb (stream-ordered)
    bf16* Wqkv_t = (bf16*)(ws + 8388608);
    bf16* Wout_t = (bf16*)(ws + 14680064);
    bf16* Qb     = (bf16*)(ws + 16777216);
    bf16* Kb     = (bf16*)(ws + 25165824);
    bf16* Vt     = (bf16*)(ws + 33554432);         // transposed: [b,h,d,s]

    cast_bf16_k<<<2048, 256, 0, stream>>>(x, Xb);
    transpose_cast_k<<<dim3(48, 16), 256, 0, stream>>>(Wqkv, Wqkv_t, DMODEL, 3 * DMODEL);
    transpose_cast_k<<<dim3(16, 16), 256, 0, stream>>>(Wout, Wout_t, DMODEL, DMODEL);
    qkv_mfma_k<<<dim3(24, 32), 256, 0, stream>>>(Xb, Wqkv_t, bqkv, Qb, Kb, Vt);
    attn_mfma_k<<<NB * NHEAD * 8, 256, 0, stream>>>(Qb, Kb, Vt, Ab);
    out_mfma_k<<<dim3(8, 32), 256, 0, stream>>>(Ab, Wout_t, bout, out);
}

// Round 10
// 186.529 us; speedup vs baseline: 1.1373x; 1.1373x over previous
//
#include <hip/hip_runtime.h>
#include <hip/hip_bf16.h>

#define NB 8
#define SEQ 512
#define DMODEL 1024
#define NHEAD 16
#define HDIM 64
typedef __hip_bfloat16 bf16;
typedef __attribute__((ext_vector_type(8))) short short8;
typedef __attribute__((ext_vector_type(4))) float f32x4;

__device__ __forceinline__ void glds16(const void* g, void* l) {
    __builtin_amdgcn_global_load_lds(
        (const __attribute__((address_space(1))) unsigned int*)g,
        (__attribute__((address_space(3))) unsigned int*)l, 16, 0, 0);
}

// ---------------- fp32 -> bf16 cast (X), 8 elems/thread
__global__ __launch_bounds__(256)
void cast_bf16_k(const float* __restrict__ X, bf16* __restrict__ Xb) {
    int i = (blockIdx.x * 256 + threadIdx.x) * 8;
    float4 v0 = *(const float4*)&X[i];
    float4 v1 = *(const float4*)&X[i + 4];
    bf16 o[8];
    o[0] = __float2bfloat16(v0.x); o[1] = __float2bfloat16(v0.y);
    o[2] = __float2bfloat16(v0.z); o[3] = __float2bfloat16(v0.w);
    o[4] = __float2bfloat16(v1.x); o[5] = __float2bfloat16(v1.y);
    o[6] = __float2bfloat16(v1.z); o[7] = __float2bfloat16(v1.w);
    *(uint4*)&Xb[i] = *(uint4*)o;
}

// ---------------- fp32 [R][C] -> bf16 [C][R] transpose (W -> W^T)
__global__ __launch_bounds__(256)
void transpose_cast_k(const float* __restrict__ W, bf16* __restrict__ Wt,
                      int R, int C) {
    __shared__ float t[64][65];
    int k0 = blockIdx.y * 64, n0 = blockIdx.x * 64;
    int c = threadIdx.x & 63, r = threadIdx.x >> 6;
    #pragma unroll 4
    for (int i = 0; i < 16; ++i)
        t[r + i * 4][c] = W[(size_t)(k0 + r + i * 4) * C + n0 + c];
    __syncthreads();
    #pragma unroll 4
    for (int i = 0; i < 16; ++i)
        Wt[(size_t)(n0 + r + i * 4) * R + k0 + c] = __float2bfloat16(t[c][r + i * 4]);
}

// ================= MFMA GEMM mainloop, single-buffered (r7-proven) ========
// C[128x128]/block, 4 waves (2x2), BK=64, 16 K-steps. Shared buffers are
// declared by the caller (Asm_, Bsm_: 8192 shorts each).
#define GEMM_MAINLOOP_SB(Agp, Bgp, Asm_, Bsm_)                                \
    int tid = threadIdx.x;                                                    \
    int lane = tid & 63, wid = tid >> 6;                                      \
    int wr = wid >> 1, wc = wid & 1;                                          \
    int lj = lane & 15, li = lane >> 4;                                       \
    int srow = lane >> 3, ssl = lane & 7;                                     \
    f32x4 acc[4][4] = {};                                                     \
    for (int ks = 0; ks < 16; ++ks) {                                         \
        int k0 = ks * 64;                                                     \
        _Pragma("unroll")                                                     \
        for (int q = 0; q < 4; ++q) {                                         \
            int seg = wid * 4 + q;                                            \
            int row = seg * 8 + srow;                                         \
            int cg = ssl ^ (row & 7);                                         \
            glds16(Agp + ((size_t)(m0 + row) * 1024 + k0 + cg * 8),           \
                   (char*)(Asm_) + seg * 1024);                               \
            glds16(Bgp + ((size_t)(n0 + row) * 1024 + k0 + cg * 8),           \
                   (char*)(Bsm_) + seg * 1024);                               \
        }                                                                     \
        __syncthreads();                                                      \
        _Pragma("unroll")                                                     \
        for (int kk = 0; kk < 2; ++kk) {                                      \
            short8 af[4], bfr[4];                                             \
            _Pragma("unroll")                                                 \
            for (int mf = 0; mf < 4; ++mf) {                                  \
                int r = wr * 64 + mf * 16 + lj;                               \
                int ck = kk * 4 + li;                                         \
                af[mf] = *(const short8*)((const char*)(Asm_) +               \
                          (r * 128 + ((ck ^ (r & 7)) * 16)));                 \
            }                                                                 \
            _Pragma("unroll")                                                 \
            for (int nf = 0; nf < 4; ++nf) {                                  \
                int r = wc * 64 + nf * 16 + lj;                               \
                int ck = kk * 4 + li;                                         \
                bfr[nf] = *(const short8*)((const char*)(Bsm_) +              \
                          (r * 128 + ((ck ^ (r & 7)) * 16)));                 \
            }                                                                 \
            _Pragma("unroll")                                                 \
            for (int mf = 0; mf < 4; ++mf)                                    \
                _Pragma("unroll")                                             \
                for (int nf = 0; nf < 4; ++nf)                                \
                    acc[mf][nf] = __builtin_amdgcn_mfma_f32_16x16x32_bf16(    \
                        af[mf], bfr[nf], acc[mf][nf], 0, 0, 0);               \
        }                                                                     \
        __syncthreads();                                                      \
    }

// ---------------- QKV GEMM (M=4096, N=3072) + bias + RoPE epilogue
// V written TRANSPOSED Vt[b,h,d,s]: tile goes through LDS for coalesced
// 256B-row stores (was 2-byte scatter). Q/K use __sincosf (HW trig).
__global__ __launch_bounds__(256)
void qkv_mfma_k(const bf16* __restrict__ Xb, const bf16* __restrict__ Wt,
                const float* __restrict__ bias,
                bf16* __restrict__ Qb, bf16* __restrict__ Kb, bf16* __restrict__ Vt) {
    __shared__ __align__(16) short SM[16640];   // 32KB mainloop / 33.3KB V-epi
    short* Asm = SM;
    short* Bsm = SM + 8192;
    int m0 = blockIdx.y * 128, n0 = blockIdx.x * 128;
    GEMM_MAINLOOP_SB(Xb, Wt, Asm, Bsm)
    int c = n0 >> 10;                 // uniform per block (boundaries % 128)
    if (c == 2) {
        // -------- V path: LDS transpose -> coalesced Vt stores
        short (*Vl)[130] = (short(*)[130])SM;   // last mainloop barrier passed
        #pragma unroll
        for (int nf = 0; nf < 4; ++nf) {
            int cl = wc * 64 + nf * 16 + lj;            // block-local col
            float bv = bias[n0 + cl];
            #pragma unroll
            for (int mf = 0; mf < 4; ++mf)
                #pragma unroll
                for (int j = 0; j < 4; ++j) {
                    int ml = wr * 64 + mf * 16 + li * 4 + j;
                    *(bf16*)&Vl[cl][ml] = __float2bfloat16(acc[mf][nf][j] + bv);
                }
        }
        __syncthreads();
        int bb = m0 >> 9, s0 = m0 & 511;
        int hbase = (n0 & 1023) >> 6;
        #pragma unroll
        for (int it = 0; it < 8; ++it) {
            int cl = it * 16 + wid * 4 + li;            // row 0..127
            int off = lj * 8;                           // 8 shorts = 16 B
            uint4 v = *(const uint4*)&Vl[cl][off];
            int hsub = cl >> 6, p = cl & 63;
            size_t dst = ((size_t)(bb * NHEAD + hbase + hsub) * HDIM + p) * SEQ
                         + s0 + off;
            *(uint4*)&Vt[dst] = v;
        }
    } else {
        // -------- Q/K path: RoPE with HW sincos
        int ncol = n0 + wc * 64;
        int h = (ncol & 1023) >> 6;
        bf16* dst = (c == 0) ? Qb : Kb;
        #pragma unroll
        for (int nf = 0; nf < 2; ++nf) {
            int p = nf * 16 + lj;
            float b1 = bias[ncol + p], b2 = bias[ncol + p + 32];
            float freq = __expf(-(float)p * 0.28782313662425574f); // 10000^(-p/32)
            #pragma unroll
            for (int mf = 0; mf < 4; ++mf) {
                #pragma unroll
                for (int j = 0; j < 4; ++j) {
                    int m = m0 + wr * 64 + mf * 16 + li * 4 + j;
                    int bb = m >> 9, s = m & 511;
                    float v1 = acc[mf][nf][j] + b1;
                    float v2 = acc[mf][nf + 2][j] + b2;
                    float sv, cv;
                    __sincosf((float)s * freq, &sv, &cv);
                    float o1 = v1 * cv - v2 * sv;
                    float o2 = v1 * sv + v2 * cv;
                    size_t base = ((size_t)(bb * NHEAD + h) * SEQ + s) * HDIM;
                    dst[base + p]      = __float2bfloat16(o1);
                    dst[base + p + 32] = __float2bfloat16(o2);
                }
            }
        }
    }
}

// ---------------- out GEMM (M=4096, N=1024) + bias -> fp32
__global__ __launch_bounds__(256)
void out_mfma_k(const bf16* __restrict__ Ab, const bf16* __restrict__ Wt,
                const float* __restrict__ bias, float* __restrict__ out) {
    __shared__ __align__(16) short SM[16384];
    short* Asm = SM;
    short* Bsm = SM + 8192;
    int m0 = blockIdx.y * 128, n0 = blockIdx.x * 128;
    GEMM_MAINLOOP_SB(Ab, Wt, Asm, Bsm)
    int col0 = n0 + wc * 64;
    #pragma unroll
    for (int nf = 0; nf < 4; ++nf) {
        int col = col0 + nf * 16 + lj;
        float bv = bias[col];
        #pragma unroll
        for (int mf = 0; mf < 4; ++mf)
            #pragma unroll
            for (int j = 0; j < 4; ++j) {
                int m = m0 + wr * 64 + mf * 16 + li * 4 + j;
                out[(size_t)m * DMODEL + col] = acc[mf][nf][j] + bv;
            }
    }
}

// ---------------- MFMA flash attention (r7-proven, single-buffered) -------
__global__ __launch_bounds__(256)
void attn_mfma_k(const bf16* __restrict__ Qb, const bf16* __restrict__ Kb,
                 const bf16* __restrict__ Vt, bf16* __restrict__ Ab) {
    __shared__ __align__(16) short Qsm[64 * 64];
    __shared__ __align__(16) short Ksm[64 * 64];
    __shared__ __align__(16) short Vsm[64 * 64];
    __shared__ __align__(16) short Psm[64 * 64];
    int tid = threadIdx.x;
    int lane = tid & 63, wid = tid >> 6;
    int lj = lane & 15, li = lane >> 4;
    int bh = blockIdx.x >> 3, qt = blockIdx.x & 7;
    const bf16* Qp = Qb + ((size_t)bh * SEQ + qt * 64) * HDIM;
    const bf16* Kp = Kb + (size_t)bh * SEQ * HDIM;
    const bf16* Vp = Vt + (size_t)bh * HDIM * SEQ;
    int srow = lane >> 3, ssl = lane & 7;
    #pragma unroll
    for (int q = 0; q < 2; ++q) {                 // stage Q once (swizzled)
        int seg = wid * 2 + q;
        int row = seg * 8 + srow;
        int cg = ssl ^ (row & 7);
        glds16(Qp + ((size_t)row * 64 + cg * 8), (char*)Qsm + seg * 1024);
    }
    float m_[4], l_[4];
    f32x4 acc_o[4] = {};
    #pragma unroll
    for (int j = 0; j < 4; ++j) { m_[j] = -1e30f; l_[j] = 0.f; }
    __syncthreads();
    for (int kt = 0; kt < 8; ++kt) {
        #pragma unroll
        for (int q = 0; q < 2; ++q) {             // stage K-tile + V^T-tile
            int seg = wid * 2 + q;
            int row = seg * 8 + srow;
            int cg = ssl ^ (row & 7);
            glds16(Kp + ((size_t)(kt * 64 + row) * 64 + cg * 8),
                   (char*)Ksm + seg * 1024);
            glds16(Vp + ((size_t)row * SEQ + kt * 64 + cg * 8),
                   (char*)Vsm + seg * 1024);
        }
        __syncthreads();
        f32x4 sacc[4] = {};
        #pragma unroll
        for (int kk = 0; kk < 2; ++kk) {
            int r = wid * 16 + lj;
            int ck = kk * 4 + li;
            short8 af = *(const short8*)((const char*)Qsm +
                         (r * 128 + ((ck ^ (r & 7)) * 16)));
            #pragma unroll
            for (int nf = 0; nf < 4; ++nf) {
                int rb = nf * 16 + lj;
                short8 kf = *(const short8*)((const char*)Ksm +
                             (rb * 128 + ((ck ^ (rb & 7)) * 16)));
                sacc[nf] = __builtin_amdgcn_mfma_f32_16x16x32_bf16(af, kf, sacc[nf], 0, 0, 0);
            }
        }
        float p[4][4];
        #pragma unroll
        for (int j = 0; j < 4; ++j) {
            float s0 = sacc[0][j] * 0.125f, s1 = sacc[1][j] * 0.125f;
            float s2 = sacc[2][j] * 0.125f, s3 = sacc[3][j] * 0.125f;
            float tm = fmaxf(fmaxf(s0, s1), fmaxf(s2, s3));
            tm = fmaxf(tm, __shfl_xor(tm, 1));
            tm = fmaxf(tm, __shfl_xor(tm, 2));
            tm = fmaxf(tm, __shfl_xor(tm, 4));
            tm = fmaxf(tm, __shfl_xor(tm, 8));
            float mn = fmaxf(m_[j], tm);
            float sc = __expf(m_[j] - mn);
            p[0][j] = __expf(s0 - mn); p[1][j] = __expf(s1 - mn);
            p[2][j] = __expf(s2 - mn); p[3][j] = __expf(s3 - mn);
            float ts = p[0][j] + p[1][j] + p[2][j] + p[3][j];
            ts += __shfl_xor(ts, 1); ts += __shfl_xor(ts, 2);
            ts += __shfl_xor(ts, 4); ts += __shfl_xor(ts, 8);
            l_[j] = l_[j] * sc + ts;
            m_[j] = mn;
            acc_o[0][j] *= sc; acc_o[1][j] *= sc;
            acc_o[2][j] *= sc; acc_o[3][j] *= sc;
        }
        #pragma unroll
        for (int nf = 0; nf < 4; ++nf)
            #pragma unroll
            for (int j = 0; j < 4; ++j) {
                int row = wid * 16 + li * 4 + j;
                int col = nf * 16 + lj;
                int cl = col >> 3;
                *(bf16*)((char*)Psm + row * 128 + ((cl ^ (row & 7)) * 16) +
                         (col & 7) * 2) = __float2bfloat16(p[nf][j]);
            }
        #pragma unroll
        for (int kk = 0; kk < 2; ++kk) {
            int r = wid * 16 + lj;
            int ck = kk * 4 + li;
            short8 pa = *(const short8*)((const char*)Psm +
                         (r * 128 + ((ck ^ (r & 7)) * 16)));
            #pragma unroll
            for (int nf = 0; nf < 4; ++nf) {
                int rb = nf * 16 + lj;
                short8 vf = *(const short8*)((const char*)Vsm +
                             (rb * 128 + ((ck ^ (rb & 7)) * 16)));
                acc_o[nf] = __builtin_amdgcn_mfma_f32_16x16x32_bf16(pa, vf, acc_o[nf], 0, 0, 0);
            }
        }
        __syncthreads();
    }
    int b = bh >> 4, h = bh & 15;
    #pragma unroll
    for (int j = 0; j < 4; ++j) {
        float inv = 1.0f / l_[j];
        int s = qt * 64 + wid * 16 + li * 4 + j;
        #pragma unroll
        for (int nf = 0; nf < 4; ++nf) {
            int d = nf * 16 + lj;
            Ab[((size_t)b * SEQ + s) * DMODEL + h * 64 + d] =
                __float2bfloat16(acc_o[nf][j] * inv);
        }
    }
}

extern "C" void kernel_launch(void* const* d_in, const int* in_sizes, int n_in,
                              void* d_out, int out_size, void* d_ws, size_t ws_size,
                              hipStream_t stream) {
    const float *x = nullptr, *Wqkv = nullptr, *bqkv = nullptr,
                *Wout = nullptr, *bout = nullptr;
    for (int i = 0; i < n_in; ++i) {
        switch (in_sizes[i]) {
            case NB * SEQ * DMODEL:   x    = (const float*)d_in[i]; break;
            case DMODEL * 3 * DMODEL: Wqkv = (const float*)d_in[i]; break;
            case 3 * DMODEL:          bqkv = (const float*)d_in[i]; break;
            case DMODEL * DMODEL:     Wout = (const float*)d_in[i]; break;
            case DMODEL:              bout = (const float*)d_in[i]; break;
        }
    }
    if (!x)    x    = (const float*)d_in[0];
    if (!Wqkv) Wqkv = (const float*)d_in[1];
    if (!bqkv) bqkv = (const float*)d_in[2];
    if (!Wout) Wout = (const float*)d_in[3];
    if (!bout) bout = (const float*)d_in[4];
    float* out = (float*)d_out;

    // ws layout, 40 MB peak (proven footprint):
    // [0,8M)   Xb bf16 — dead after qkv_mfma; Ab (bf16) aliases it
    // [8,14M)  Wqkv_t | [14,16M) Wout_t | [16,24M) Qb | [24,32M) Kb | [32,40M) Vt
    char* ws = (char*)d_ws;
    bf16* Xb     = (bf16*)(ws);
    bf16* Ab     = (bf16*)(ws);                    // aliases Xb (stream-ordered)
    bf16* Wqkv_t = (bf16*)(ws + 8388608);
    bf16* Wout_t = (bf16*)(ws + 14680064);
    bf16* Qb     = (bf16*)(ws + 16777216);
    bf16* Kb     = (bf16*)(ws + 25165824);
    bf16* Vt     = (bf16*)(ws + 33554432);         // transposed: [b,h,d,s]

    cast_bf16_k<<<2048, 256, 0, stream>>>(x, Xb);
    transpose_cast_k<<<dim3(48, 16), 256, 0, stream>>>(Wqkv, Wqkv_t, DMODEL, 3 * DMODEL);
    transpose_cast_k<<<dim3(16, 16), 256, 0, stream>>>(Wout, Wout_t, DMODEL, DMODEL);
    qkv_mfma_k<<<dim3(24, 32), 256, 0, stream>>>(Xb, Wqkv_t, bqkv, Qb, Kb, Vt);
    attn_mfma_k<<<NB * NHEAD * 8, 256, 0, stream>>>(Qb, Kb, Vt, Ab);
    out_mfma_k<<<dim3(8, 32), 256, 0, stream>>>(Ab, Wout_t, bout, out);
}

// Round 11
// 170.597 us; speedup vs baseline: 1.2435x; 1.0934x over previous
//
#include <hip/hip_runtime.h>
#include <hip/hip_bf16.h>

#define NB 8
#define SEQ 512
#define DMODEL 1024
#define NHEAD 16
#define HDIM 64
typedef __hip_bfloat16 bf16;
typedef __attribute__((ext_vector_type(8))) short short8;
typedef __attribute__((ext_vector_type(4))) float f32x4;

__device__ __forceinline__ void glds16(const void* g, void* l) {
    __builtin_amdgcn_global_load_lds(
        (const __attribute__((address_space(1))) unsigned int*)g,
        (__attribute__((address_space(3))) unsigned int*)l, 16, 0, 0);
}

// ---------------- fp32 -> bf16 cast (X), 8 elems/thread
__global__ __launch_bounds__(256)
void cast_bf16_k(const float* __restrict__ X, bf16* __restrict__ Xb) {
    int i = (blockIdx.x * 256 + threadIdx.x) * 8;
    float4 v0 = *(const float4*)&X[i];
    float4 v1 = *(const float4*)&X[i + 4];
    bf16 o[8];
    o[0] = __float2bfloat16(v0.x); o[1] = __float2bfloat16(v0.y);
    o[2] = __float2bfloat16(v0.z); o[3] = __float2bfloat16(v0.w);
    o[4] = __float2bfloat16(v1.x); o[5] = __float2bfloat16(v1.y);
    o[6] = __float2bfloat16(v1.z); o[7] = __float2bfloat16(v1.w);
    *(uint4*)&Xb[i] = *(uint4*)o;
}

// ---------------- fp32 [R][C] -> bf16 [C][R] transpose (W -> W^T)
__global__ __launch_bounds__(256)
void transpose_cast_k(const float* __restrict__ W, bf16* __restrict__ Wt,
                      int R, int C) {
    __shared__ float t[64][65];
    int k0 = blockIdx.y * 64, n0 = blockIdx.x * 64;
    int c = threadIdx.x & 63, r = threadIdx.x >> 6;
    #pragma unroll 4
    for (int i = 0; i < 16; ++i)
        t[r + i * 4][c] = W[(size_t)(k0 + r + i * 4) * C + n0 + c];
    __syncthreads();
    #pragma unroll 4
    for (int i = 0; i < 16; ++i)
        Wt[(size_t)(n0 + r + i * 4) * R + k0 + c] = __float2bfloat16(t[c][r + i * 4]);
}

// ======= MFMA GEMM mainloop, 2-deep pipeline with COUNTED vmcnt (T4) ======
// C[128x128]/block, 4 waves, BK=64, 16 K-steps. LDS: 2 halves per operand
// (64KB). stage(t+1) issued, then vmcnt(8) waits ONLY tile-t's 8 loads —
// t+1's loads stay in flight across the raw s_barrier (no vmcnt(0) drain).
// Tail: lgkmcnt(0)+barrier guarantees all ds_reads of half `cur` retired
// before any wave's next-iter glds overwrites it. asm memory clobbers fence
// compiler-level reordering around the raw barriers.
#define GEMM_MAINLOOP_PIPE(Agp, Bgp, Asm_, Bsm_)                              \
    int tid = threadIdx.x;                                                    \
    int lane = tid & 63, wid = tid >> 6;                                      \
    int wr = wid >> 1, wc = wid & 1;                                          \
    int lj = lane & 15, li = lane >> 4;                                       \
    int srow = lane >> 3, ssl = lane & 7;                                     \
    f32x4 acc[4][4] = {};                                                     \
    _Pragma("unroll")                                                         \
    for (int q = 0; q < 4; ++q) {                                             \
        int seg = wid * 4 + q;                                                \
        int row = seg * 8 + srow;                                             \
        int cg = ssl ^ (row & 7);                                             \
        glds16(Agp + ((size_t)(m0 + row) * 1024 + cg * 8),                    \
               (char*)(Asm_) + seg * 1024);                                   \
        glds16(Bgp + ((size_t)(n0 + row) * 1024 + cg * 8),                    \
               (char*)(Bsm_) + seg * 1024);                                   \
    }                                                                         \
    for (int ks = 0; ks < 16; ++ks) {                                         \
        int cur = ks & 1;                                                     \
        if (ks + 1 < 16) {                                                    \
            int k0 = (ks + 1) * 64;                                           \
            _Pragma("unroll")                                                 \
            for (int q = 0; q < 4; ++q) {                                     \
                int seg = wid * 4 + q;                                        \
                int row = seg * 8 + srow;                                     \
                int cg = ssl ^ (row & 7);                                     \
                glds16(Agp + ((size_t)(m0 + row) * 1024 + k0 + cg * 8),       \
                       (char*)(Asm_) + (cur ^ 1) * 16384 + seg * 1024);       \
                glds16(Bgp + ((size_t)(n0 + row) * 1024 + k0 + cg * 8),       \
                       (char*)(Bsm_) + (cur ^ 1) * 16384 + seg * 1024);       \
            }                                                                 \
            asm volatile("s_waitcnt vmcnt(8)" ::: "memory");                  \
        } else {                                                              \
            asm volatile("s_waitcnt vmcnt(0)" ::: "memory");                  \
        }                                                                     \
        __builtin_amdgcn_s_barrier();                                         \
        asm volatile("" ::: "memory");                                        \
        const char* Abuf_ = (const char*)(Asm_) + cur * 16384;                \
        const char* Bbuf_ = (const char*)(Bsm_) + cur * 16384;                \
        _Pragma("unroll")                                                     \
        for (int kk = 0; kk < 2; ++kk) {                                      \
            short8 af[4], bfr[4];                                             \
            _Pragma("unroll")                                                 \
            for (int mf = 0; mf < 4; ++mf) {                                  \
                int r = wr * 64 + mf * 16 + lj;                               \
                int ck = kk * 4 + li;                                         \
                af[mf] = *(const short8*)(Abuf_ +                             \
                          (r * 128 + ((ck ^ (r & 7)) * 16)));                 \
            }                                                                 \
            _Pragma("unroll")                                                 \
            for (int nf = 0; nf < 4; ++nf) {                                  \
                int r = wc * 64 + nf * 16 + lj;                               \
                int ck = kk * 4 + li;                                         \
                bfr[nf] = *(const short8*)(Bbuf_ +                            \
                          (r * 128 + ((ck ^ (r & 7)) * 16)));                 \
            }                                                                 \
            _Pragma("unroll")                                                 \
            for (int mf = 0; mf < 4; ++mf)                                    \
                _Pragma("unroll")                                             \
                for (int nf = 0; nf < 4; ++nf)                                \
                    acc[mf][nf] = __builtin_amdgcn_mfma_f32_16x16x32_bf16(    \
                        af[mf], bfr[nf], acc[mf][nf], 0, 0, 0);               \
        }                                                                     \
        asm volatile("s_waitcnt lgkmcnt(0)" ::: "memory");                    \
        __builtin_amdgcn_s_barrier();                                         \
        asm volatile("" ::: "memory");                                        \
    }

// ---------------- QKV GEMM (M=4096, N=3072) + bias + RoPE epilogue
// V written TRANSPOSED Vt[b,h,d,s] via LDS for coalesced stores.
// RoPE: __sincosf at j=0 + angle-addition recurrence for j=1..3.
__global__ __launch_bounds__(256)
void qkv_mfma_k(const bf16* __restrict__ Xb, const bf16* __restrict__ Wt,
                const float* __restrict__ bias,
                bf16* __restrict__ Qb, bf16* __restrict__ Kb, bf16* __restrict__ Vt) {
    __shared__ __align__(16) short SM[32768];   // 64KB: 2x16KB A + 2x16KB B
    short* Asm = SM;
    short* Bsm = SM + 16384;
    int m0 = blockIdx.y * 128, n0 = blockIdx.x * 128;
    GEMM_MAINLOOP_PIPE(Xb, Wt, Asm, Bsm)
    int c = n0 >> 10;                 // uniform per block (boundaries % 128)
    if (c == 2) {
        // -------- V path: LDS transpose -> coalesced Vt stores
        short (*Vl)[130] = (short(*)[130])SM;   // final barrier passed
        #pragma unroll
        for (int nf = 0; nf < 4; ++nf) {
            int cl = wc * 64 + nf * 16 + lj;            // block-local col
            float bv = bias[n0 + cl];
            #pragma unroll
            for (int mf = 0; mf < 4; ++mf)
                #pragma unroll
                for (int j = 0; j < 4; ++j) {
                    int ml = wr * 64 + mf * 16 + li * 4 + j;
                    *(bf16*)&Vl[cl][ml] = __float2bfloat16(acc[mf][nf][j] + bv);
                }
        }
        __syncthreads();
        int bb = m0 >> 9, s0 = m0 & 511;
        int hbase = (n0 & 1023) >> 6;
        #pragma unroll
        for (int it = 0; it < 8; ++it) {
            int cl = it * 16 + wid * 4 + li;            // row 0..127
            int off = lj * 8;                           // 8 shorts = 16 B
            uint4 v = *(const uint4*)&Vl[cl][off];
            int hsub = cl >> 6, p = cl & 63;
            size_t dst = ((size_t)(bb * NHEAD + hbase + hsub) * HDIM + p) * SEQ
                         + s0 + off;
            *(uint4*)&Vt[dst] = v;
        }
    } else {
        // -------- Q/K path: RoPE with HW sincos + rotation recurrence
        int ncol = n0 + wc * 64;
        int h = (ncol & 1023) >> 6;
        bf16* dst = (c == 0) ? Qb : Kb;
        #pragma unroll
        for (int nf = 0; nf < 2; ++nf) {
            int p = nf * 16 + lj;
            float b1 = bias[ncol + p], b2 = bias[ncol + p + 32];
            float freq = __expf(-(float)p * 0.28782313662425574f); // 10000^(-p/32)
            float sf, cf;
            __sincosf(freq, &sf, &cf);                  // per-step rotation
            #pragma unroll
            for (int mf = 0; mf < 4; ++mf) {
                int mb = m0 + wr * 64 + mf * 16 + li * 4;   // j=0 row
                int bb = mb >> 9, s0 = mb & 511;            // const over j
                float sv, cv;
                __sincosf((float)s0 * freq, &sv, &cv);
                #pragma unroll
                for (int j = 0; j < 4; ++j) {
                    float v1 = acc[mf][nf][j] + b1;
                    float v2 = acc[mf][nf + 2][j] + b2;
                    float o1 = v1 * cv - v2 * sv;
                    float o2 = v1 * sv + v2 * cv;
                    size_t base = ((size_t)(bb * NHEAD + h) * SEQ + s0 + j) * HDIM;
                    dst[base + p]      = __float2bfloat16(o1);
                    dst[base + p + 32] = __float2bfloat16(o2);
                    float cn = cv * cf - sv * sf;       // rotate angle by freq
                    sv = sv * cf + cv * sf;
                    cv = cn;
                }
            }
        }
    }
}

// ---------------- out GEMM (M=4096, N=1024) + bias -> fp32
__global__ __launch_bounds__(256)
void out_mfma_k(const bf16* __restrict__ Ab, const bf16* __restrict__ Wt,
                const float* __restrict__ bias, float* __restrict__ out) {
    __shared__ __align__(16) short SM[32768];
    short* Asm = SM;
    short* Bsm = SM + 16384;
    int m0 = blockIdx.y * 128, n0 = blockIdx.x * 128;
    GEMM_MAINLOOP_PIPE(Ab, Wt, Asm, Bsm)
    int col0 = n0 + wc * 64;
    #pragma unroll
    for (int nf = 0; nf < 4; ++nf) {
        int col = col0 + nf * 16 + lj;
        float bv = bias[col];
        #pragma unroll
        for (int mf = 0; mf < 4; ++mf)
            #pragma unroll
            for (int j = 0; j < 4; ++j) {
                int m = m0 + wr * 64 + mf * 16 + li * 4 + j;
                out[(size_t)m * DMODEL + col] = acc[mf][nf][j] + bv;
            }
    }
}

// ---------------- MFMA flash attention (r10-proven, unchanged) ------------
__global__ __launch_bounds__(256)
void attn_mfma_k(const bf16* __restrict__ Qb, const bf16* __restrict__ Kb,
                 const bf16* __restrict__ Vt, bf16* __restrict__ Ab) {
    __shared__ __align__(16) short Qsm[64 * 64];
    __shared__ __align__(16) short Ksm[64 * 64];
    __shared__ __align__(16) short Vsm[64 * 64];
    __shared__ __align__(16) short Psm[64 * 64];
    int tid = threadIdx.x;
    int lane = tid & 63, wid = tid >> 6;
    int lj = lane & 15, li = lane >> 4;
    int bh = blockIdx.x >> 3, qt = blockIdx.x & 7;
    const bf16* Qp = Qb + ((size_t)bh * SEQ + qt * 64) * HDIM;
    const bf16* Kp = Kb + (size_t)bh * SEQ * HDIM;
    const bf16* Vp = Vt + (size_t)bh * HDIM * SEQ;
    int srow = lane >> 3, ssl = lane & 7;
    #pragma unroll
    for (int q = 0; q < 2; ++q) {                 // stage Q once (swizzled)
        int seg = wid * 2 + q;
        int row = seg * 8 + srow;
        int cg = ssl ^ (row & 7);
        glds16(Qp + ((size_t)row * 64 + cg * 8), (char*)Qsm + seg * 1024);
    }
    float m_[4], l_[4];
    f32x4 acc_o[4] = {};
    #pragma unroll
    for (int j = 0; j < 4; ++j) { m_[j] = -1e30f; l_[j] = 0.f; }
    __syncthreads();
    for (int kt = 0; kt < 8; ++kt) {
        #pragma unroll
        for (int q = 0; q < 2; ++q) {             // stage K-tile + V^T-tile
            int seg = wid * 2 + q;
            int row = seg * 8 + srow;
            int cg = ssl ^ (row & 7);
            glds16(Kp + ((size_t)(kt * 64 + row) * 64 + cg * 8),
                   (char*)Ksm + seg * 1024);
            glds16(Vp + ((size_t)row * SEQ + kt * 64 + cg * 8),
                   (char*)Vsm + seg * 1024);
        }
        __syncthreads();
        f32x4 sacc[4] = {};
        #pragma unroll
        for (int kk = 0; kk < 2; ++kk) {
            int r = wid * 16 + lj;
            int ck = kk * 4 + li;
            short8 af = *(const short8*)((const char*)Qsm +
                         (r * 128 + ((ck ^ (r & 7)) * 16)));
            #pragma unroll
            for (int nf = 0; nf < 4; ++nf) {
                int rb = nf * 16 + lj;
                short8 kf = *(const short8*)((const char*)Ksm +
                             (rb * 128 + ((ck ^ (rb & 7)) * 16)));
                sacc[nf] = __builtin_amdgcn_mfma_f32_16x16x32_bf16(af, kf, sacc[nf], 0, 0, 0);
            }
        }
        float p[4][4];
        #pragma unroll
        for (int j = 0; j < 4; ++j) {
            float s0 = sacc[0][j] * 0.125f, s1 = sacc[1][j] * 0.125f;
            float s2 = sacc[2][j] * 0.125f, s3 = sacc[3][j] * 0.125f;
            float tm = fmaxf(fmaxf(s0, s1), fmaxf(s2, s3));
            tm = fmaxf(tm, __shfl_xor(tm, 1));
            tm = fmaxf(tm, __shfl_xor(tm, 2));
            tm = fmaxf(tm, __shfl_xor(tm, 4));
            tm = fmaxf(tm, __shfl_xor(tm, 8));
            float mn = fmaxf(m_[j], tm);
            float sc = __expf(m_[j] - mn);
            p[0][j] = __expf(s0 - mn); p[1][j] = __expf(s1 - mn);
            p[2][j] = __expf(s2 - mn); p[3][j] = __expf(s3 - mn);
            float ts = p[0][j] + p[1][j] + p[2][j] + p[3][j];
            ts += __shfl_xor(ts, 1); ts += __shfl_xor(ts, 2);
            ts += __shfl_xor(ts, 4); ts += __shfl_xor(ts, 8);
            l_[j] = l_[j] * sc + ts;
            m_[j] = mn;
            acc_o[0][j] *= sc; acc_o[1][j] *= sc;
            acc_o[2][j] *= sc; acc_o[3][j] *= sc;
        }
        #pragma unroll
        for (int nf = 0; nf < 4; ++nf)
            #pragma unroll
            for (int j = 0; j < 4; ++j) {
                int row = wid * 16 + li * 4 + j;
                int col = nf * 16 + lj;
                int cl = col >> 3;
                *(bf16*)((char*)Psm + row * 128 + ((cl ^ (row & 7)) * 16) +
                         (col & 7) * 2) = __float2bfloat16(p[nf][j]);
            }
        #pragma unroll
        for (int kk = 0; kk < 2; ++kk) {
            int r = wid * 16 + lj;
            int ck = kk * 4 + li;
            short8 pa = *(const short8*)((const char*)Psm +
                         (r * 128 + ((ck ^ (r & 7)) * 16)));
            #pragma unroll
            for (int nf = 0; nf < 4; ++nf) {
                int rb = nf * 16 + lj;
                short8 vf = *(const short8*)((const char*)Vsm +
                             (rb * 128 + ((ck ^ (rb & 7)) * 16)));
                acc_o[nf] = __builtin_amdgcn_mfma_f32_16x16x32_bf16(pa, vf, acc_o[nf], 0, 0, 0);
            }
        }
        __syncthreads();
    }
    int b = bh >> 4, h = bh & 15;
    #pragma unroll
    for (int j = 0; j < 4; ++j) {
        float inv = 1.0f / l_[j];
        int s = qt * 64 + wid * 16 + li * 4 + j;
        #pragma unroll
        for (int nf = 0; nf < 4; ++nf) {
            int d = nf * 16 + lj;
            Ab[((size_t)b * SEQ + s) * DMODEL + h * 64 + d] =
                __float2bfloat16(acc_o[nf][j] * inv);
        }
    }
}

extern "C" void kernel_launch(void* const* d_in, const int* in_sizes, int n_in,
                              void* d_out, int out_size, void* d_ws, size_t ws_size,
                              hipStream_t stream) {
    const float *x = nullptr, *Wqkv = nullptr, *bqkv = nullptr,
                *Wout = nullptr, *bout = nullptr;
    for (int i = 0; i < n_in; ++i) {
        switch (in_sizes[i]) {
            case NB * SEQ * DMODEL:   x    = (const float*)d_in[i]; break;
            case DMODEL * 3 * DMODEL: Wqkv = (const float*)d_in[i]; break;
            case 3 * DMODEL:          bqkv = (const float*)d_in[i]; break;
            case DMODEL * DMODEL:     Wout = (const float*)d_in[i]; break;
            case DMODEL:              bout = (const float*)d_in[i]; break;
        }
    }
    if (!x)    x    = (const float*)d_in[0];
    if (!Wqkv) Wqkv = (const float*)d_in[1];
    if (!bqkv) bqkv = (const float*)d_in[2];
    if (!Wout) Wout = (const float*)d_in[3];
    if (!bout) bout = (const float*)d_in[4];
    float* out = (float*)d_out;

    // ws layout, 40 MB peak (proven footprint):
    // [0,8M)   Xb bf16 — dead after qkv_mfma; Ab (bf16) aliases it
    // [8,14M)  Wqkv_t | [14,16M) Wout_t | [16,24M) Qb | [24,32M) Kb | [32,40M) Vt
    char* ws = (char*)d_ws;
    bf16* Xb     = (bf16*)(ws);
    bf16* Ab     = (bf16*)(ws);                    // aliases Xb (stream-ordered)
    bf16* Wqkv_t = (bf16*)(ws + 8388608);
    bf16* Wout_t = (bf16*)(ws + 14680064);
    bf16* Qb     = (bf16*)(ws + 16777216);
    bf16* Kb     = (bf16*)(ws + 25165824);
    bf16* Vt     = (bf16*)(ws + 33554432);         // transposed: [b,h,d,s]

    cast_bf16_k<<<2048, 256, 0, stream>>>(x, Xb);
    transpose_cast_k<<<dim3(48, 16), 256, 0, stream>>>(Wqkv, Wqkv_t, DMODEL, 3 * DMODEL);
    transpose_cast_k<<<dim3(16, 16), 256, 0, stream>>>(Wout, Wout_t, DMODEL, DMODEL);
    qkv_mfma_k<<<dim3(24, 32), 256, 0, stream>>>(Xb, Wqkv_t, bqkv, Qb, Kb, Vt);
    attn_mfma_k<<<NB * NHEAD * 8, 256, 0, stream>>>(Qb, Kb, Vt, Ab);
    out_mfma_k<<<dim3(8, 32), 256, 0, stream>>>(Ab, Wout_t, bout, out);
}